// Round 1
// baseline (672.321 us; speedup 1.0000x reference)
//
#include <hip/hip_runtime.h>
#include <stdint.h>

#define B_ 2
#define T_ 2048
#define P_ 1024
#define H_ 16
#define D_ 128
#define C_ 2048
#define S_ 3072   // P_ + T_
#define M_ 4096   // B_*T_
#define N3_ 6144  // 3*C_

typedef unsigned short u16;
typedef __attribute__((ext_vector_type(8))) short short8;
typedef __attribute__((ext_vector_type(8))) __bf16 bf16x8;
typedef __attribute__((ext_vector_type(4))) float f32x4;
typedef __attribute__((ext_vector_type(4))) unsigned short u16x4;

static __device__ __forceinline__ float bf2f(u16 h) {
    union { unsigned int u; float f; } x; x.u = ((unsigned int)h) << 16; return x.f;
}
static __device__ __forceinline__ u16 f2bf(float f) {
    union { float f; unsigned int u; } x; x.f = f;
    unsigned int u = x.u;
    u += 0x7FFFu + ((u >> 16) & 1u);   // RNE
    return (u16)(u >> 16);
}

static __device__ __forceinline__ f32x4 mfma_bf16(short8 a, short8 b, f32x4 c) {
    return __builtin_amdgcn_mfma_f32_16x16x32_bf16(
        __builtin_bit_cast(bf16x8, a), __builtin_bit_cast(bf16x8, b), c, 0, 0, 0);
}

typedef __attribute__((address_space(3))) unsigned int lds_u32;
typedef const __attribute__((address_space(1))) unsigned int glb_u32;
static __device__ __forceinline__ void gload_lds16(const void* g, void* l) {
    __builtin_amdgcn_global_load_lds((glb_u32*)g, (lds_u32*)l, 16, 0, 0);
}

static __device__ __forceinline__ void storeC(float* p, float v) { *p = v; }
static __device__ __forceinline__ void storeC(u16* p, float v) { *p = f2bf(v); }

// ---------------------------------------------------------------- prep kernels

__global__ void castx_kernel(const float* __restrict__ x, u16* __restrict__ Xb) {
    int idx = blockIdx.x * 256 + threadIdx.x;          // over (M_*C_)/4
    const float4 v = ((const float4*)x)[idx];
    u16x4 o;
    o.x = f2bf(v.x); o.y = f2bf(v.y); o.z = f2bf(v.z); o.w = f2bf(v.w);
    ((u16x4*)Xb)[idx] = o;
}

// W[K,N] f32 -> Wt[N,K] bf16, 64x64 LDS tiles
__global__ void wT_kernel(const float* __restrict__ W, u16* __restrict__ Wt,
                          int Ndim, int Kdim) {
    __shared__ float tile[64][65];
    const int n0 = blockIdx.x * 64, k0 = blockIdx.y * 64;
    const int tid = threadIdx.x;
#pragma unroll
    for (int i = 0; i < 16; i++) {
        int idx = tid + i * 256;
        int r = idx >> 6, c = idx & 63;                // r: k, c: n
        tile[r][c] = W[(size_t)(k0 + r) * Ndim + n0 + c];
    }
    __syncthreads();
#pragma unroll
    for (int i = 0; i < 16; i++) {
        int idx = tid + i * 256;
        int r = idx >> 6, c = idx & 63;                // r: n, c: k
        Wt[(size_t)(n0 + r) * Kdim + k0 + c] = f2bf(tile[c][r]);
    }
}

__global__ void rope_table_kernel(float* __restrict__ cosT, float* __restrict__ sinT) {
    int idx = blockIdx.x * 256 + threadIdx.x;          // T_*64
    int t = idx >> 6, d = idx & 63;
    float inv = powf(10000.0f, -(float)d * (1.0f / 64.0f));
    float ang = (float)(P_ + t) * inv;
    cosT[idx] = cosf(ang);
    sinT[idx] = sinf(ang);
}

// RoPE Q in place; RoPE K and scatter into Kc[b,h,P_+t,d]
__global__ void rope_qk_kernel(u16* __restrict__ QKVb, u16* __restrict__ Kc,
                               const float* __restrict__ cosT,
                               const float* __restrict__ sinT) {
    int idx = blockIdx.x * 256 + threadIdx.x;          // B_*T_*H_*64
    int d = idx & 63;
    int h = (idx >> 6) & 15;
    int t = (idx >> 10) & 2047;
    int b = idx >> 21;
    size_t rowoff = (size_t)(b * T_ + t) * N3_;
    float c = cosT[(t << 6) + d], s = sinT[(t << 6) + d];
    {   // Q
        u16* p1 = QKVb + rowoff + h * 128 + d;
        float x1 = bf2f(p1[0]), x2 = bf2f(p1[64]);
        p1[0]  = f2bf(x1 * c - x2 * s);
        p1[64] = f2bf(x2 * c + x1 * s);
    }
    {   // K -> cache
        const u16* p1 = QKVb + rowoff + C_ + h * 128 + d;
        float x1 = bf2f(p1[0]), x2 = bf2f(p1[64]);
        u16* o = Kc + ((size_t)(b * H_ + h) * S_ + P_ + t) * 128 + d;
        o[0]  = f2bf(x1 * c - x2 * s);
        o[64] = f2bf(x2 * c + x1 * s);
    }
}

__global__ void pastk_kernel(const float* __restrict__ past_k, u16* __restrict__ Kc) {
    int idx = blockIdx.x * 256 + threadIdx.x;          // B_*H_*P_*D_
    int d = idx & 127;
    int p = (idx >> 7) & 1023;
    int bh = idx >> 17;
    Kc[((size_t)bh * S_ + p) * 128 + d] = f2bf(past_k[idx]);
}

// new V (bf16 in QKVb) -> Vt[b,h,d,P_+t]
__global__ void vnewT_kernel(const u16* __restrict__ QKVb, u16* __restrict__ Vt) {
    __shared__ u16 tile[64][65];
    const int t0 = blockIdx.x * 64, d0 = blockIdx.y * 64, bh = blockIdx.z;
    const int b = bh >> 4, h = bh & 15;
    const int tid = threadIdx.x;
#pragma unroll
    for (int i = 0; i < 16; i++) {
        int idx = tid + i * 256;
        int r = idx >> 6, c = idx & 63;                // r: t, c: d
        tile[r][c] = QKVb[(size_t)(b * T_ + t0 + r) * N3_ + 2 * C_ + h * 128 + d0 + c];
    }
    __syncthreads();
#pragma unroll
    for (int i = 0; i < 16; i++) {
        int idx = tid + i * 256;
        int r = idx >> 6, c = idx & 63;                // r: d, c: t
        Vt[((size_t)bh * 128 + d0 + r) * S_ + P_ + t0 + c] = tile[c][r];
    }
}

// past V f32 -> Vt[b,h,d,p]
__global__ void vpastT_kernel(const float* __restrict__ past_v, u16* __restrict__ Vt) {
    __shared__ float tile[64][65];
    const int p0 = blockIdx.x * 64, d0 = blockIdx.y * 64, bh = blockIdx.z;
    const int tid = threadIdx.x;
#pragma unroll
    for (int i = 0; i < 16; i++) {
        int idx = tid + i * 256;
        int r = idx >> 6, c = idx & 63;                // r: p, c: d
        tile[r][c] = past_v[((size_t)bh * P_ + p0 + r) * 128 + d0 + c];
    }
    __syncthreads();
#pragma unroll
    for (int i = 0; i < 16; i++) {
        int idx = tid + i * 256;
        int r = idx >> 6, c = idx & 63;                // r: d, c: p
        Vt[((size_t)bh * 128 + d0 + r) * S_ + p0 + c] = f2bf(tile[c][r]);
    }
}

// ---------------------------------------------------------------- GEMM
// C[M,N] = A[M,K] * Bt[N,K]^T ; bf16 in, OutT out. 128x128 tile, BK=64, 4 waves.
template <typename OutT>
__global__ void __launch_bounds__(256)
gemm_bt(const u16* __restrict__ A, const u16* __restrict__ Bt,
        OutT* __restrict__ Co, int Mdim, int Ndim, int Kdim) {
    __shared__ u16 ldsA[128 * 64];
    __shared__ u16 ldsB[128 * 64];
    const int nbx = Ndim >> 7;
    const int nwg = (Mdim >> 7) * nbx;
    int bid = blockIdx.x;
    int wg = (bid & 7) * (nwg >> 3) + (bid >> 3);      // XCD swizzle (nwg % 8 == 0)
    const int bm = wg / nbx, bn = wg % nbx;
    const int m0 = bm << 7, n0 = bn << 7;
    const int tid = threadIdx.x;
    const int wave = tid >> 6, lane = tid & 63;
    const int wr = wave >> 1, wc = wave & 1;

    f32x4 acc[4][4];
#pragma unroll
    for (int i = 0; i < 4; i++)
#pragma unroll
        for (int j = 0; j < 4; j++) acc[i][j] = (f32x4){0.f, 0.f, 0.f, 0.f};

    const int srow = wave * 32 + (lane >> 3);
    const int scol = (lane & 7) << 3;
    const u16* gA = A + (size_t)(m0 + srow) * Kdim + scol;
    const u16* gB = Bt + (size_t)(n0 + srow) * Kdim + scol;

    for (int k0 = 0; k0 < Kdim; k0 += 64) {
#pragma unroll
        for (int c = 0; c < 4; c++) {
            gload_lds16(gA + (size_t)(c * 8) * Kdim + k0, &ldsA[(wave * 32 + c * 8) * 64]);
            gload_lds16(gB + (size_t)(c * 8) * Kdim + k0, &ldsB[(wave * 32 + c * 8) * 64]);
        }
        __syncthreads();
#pragma unroll
        for (int kk = 0; kk < 2; kk++) {
            short8 af[4], bf[4];
#pragma unroll
            for (int i = 0; i < 4; i++) {
                int row = wr * 64 + i * 16 + (lane & 15);
                af[i] = *(const short8*)&ldsA[row * 64 + kk * 32 + ((lane >> 4) << 3)];
                int col = wc * 64 + i * 16 + (lane & 15);
                bf[i] = *(const short8*)&ldsB[col * 64 + kk * 32 + ((lane >> 4) << 3)];
            }
#pragma unroll
            for (int i = 0; i < 4; i++)
#pragma unroll
                for (int j = 0; j < 4; j++)
                    acc[i][j] = mfma_bf16(af[i], bf[j], acc[i][j]);
        }
        __syncthreads();
    }
#pragma unroll
    for (int i = 0; i < 4; i++)
#pragma unroll
        for (int j = 0; j < 4; j++) {
            int row = m0 + wr * 64 + i * 16 + ((lane >> 4) << 2);
            int col = n0 + wc * 64 + j * 16 + (lane & 15);
#pragma unroll
            for (int q = 0; q < 4; q++)
                storeC(&Co[(size_t)(row + q) * Ndim + col], acc[i][j][q]);
        }
}

// ---------------------------------------------------------------- attention
// Per block: one (b,h), 64 q rows. 4 waves x 16 q rows. KV block = 64.
__global__ void __launch_bounds__(256)
attn_kernel(const u16* __restrict__ QKVb, const u16* __restrict__ Kc,
            const u16* __restrict__ Vt, u16* __restrict__ O) {
    __shared__ u16 ldsK[64 * 128];
    __shared__ u16 ldsV[128 * 64];
    __shared__ u16 ldsP[64 * 64];

    const int nwg = B_ * H_ * (T_ / 64);               // 1024
    int bid = blockIdx.x;
    int wg = (bid & 7) * (nwg >> 3) + (bid >> 3);      // XCD swizzle
    const int qb = wg & 31;
    const int h = (wg >> 5) & 15;
    const int b = wg >> 9;
    const int tid = threadIdx.x, wave = tid >> 6, lane = tid & 63;
    const int l15 = lane & 15, l4 = lane >> 4;

    // Q fragments (A-operand), rows = wave*16 + l15
    short8 qf[4];
    {
        const u16* qptr = QKVb + (size_t)(b * T_ + qb * 64 + wave * 16 + l15) * N3_
                          + h * 128 + (l4 << 3);
#pragma unroll
        for (int s = 0; s < 4; s++) qf[s] = *(const short8*)(qptr + s * 32);
    }

    f32x4 acco[8];
#pragma unroll
    for (int n = 0; n < 8; n++) acco[n] = (f32x4){0.f, 0.f, 0.f, 0.f};
    float mrow[4], lrow[4];
#pragma unroll
    for (int q = 0; q < 4; q++) { mrow[q] = -INFINITY; lrow[q] = 0.f; }

    const u16* Kbh = Kc + (size_t)(b * H_ + h) * S_ * 128;
    const u16* Vbh = Vt + (size_t)(b * H_ + h) * 128 * S_;
    const float scale = 0.08838834764831845f;          // 1/sqrt(128)

    for (int s0 = 0; s0 < S_; s0 += 64) {
        // stage K (64 x 128) and V^T (128 x 64)
#pragma unroll
        for (int c = 0; c < 4; c++) {
            gload_lds16(Kbh + (size_t)(s0 + wave * 16 + c * 4 + l4) * 128 + (l15 << 3),
                        &ldsK[(wave * 16 + c * 4) * 128]);
            gload_lds16(Vbh + (size_t)(wave * 32 + c * 8 + (lane >> 3)) * S_ + s0 + ((lane & 7) << 3),
                        &ldsV[(wave * 32 + c * 8) * 64]);
        }
        __syncthreads();

        // QK^T : 16 q rows x 64 keys
        f32x4 accs[4];
#pragma unroll
        for (int j = 0; j < 4; j++) accs[j] = (f32x4){0.f, 0.f, 0.f, 0.f};
#pragma unroll
        for (int s = 0; s < 4; s++)
#pragma unroll
            for (int j = 0; j < 4; j++) {
                short8 kf = *(const short8*)&ldsK[(j * 16 + l15) * 128 + s * 32 + (l4 << 3)];
                accs[j] = mfma_bf16(qf[s], kf, accs[j]);
            }

        // row max (across 4 n-frags and 16 lanes of the group)
        float pmax[4];
#pragma unroll
        for (int q = 0; q < 4; q++) {
            float v = fmaxf(fmaxf(accs[0][q], accs[1][q]), fmaxf(accs[2][q], accs[3][q]));
#pragma unroll
            for (int off = 8; off >= 1; off >>= 1) v = fmaxf(v, __shfl_xor(v, off));
            pmax[q] = v * scale;
        }
        float fac[4];
#pragma unroll
        for (int q = 0; q < 4; q++) {
            float mn = fmaxf(mrow[q], pmax[q]);
            fac[q] = __expf(mrow[q] - mn);
            mrow[q] = mn;
        }
#pragma unroll
        for (int j = 0; j < 4; j++)
#pragma unroll
            for (int q = 0; q < 4; q++)
                accs[j][q] = __expf(accs[j][q] * scale - mrow[q]);
#pragma unroll
        for (int q = 0; q < 4; q++) {
            float s = accs[0][q] + accs[1][q] + accs[2][q] + accs[3][q];
#pragma unroll
            for (int off = 8; off >= 1; off >>= 1) s += __shfl_xor(s, off);
            lrow[q] = lrow[q] * fac[q] + s;
        }
#pragma unroll
        for (int n = 0; n < 8; n++)
#pragma unroll
            for (int q = 0; q < 4; q++) acco[n][q] *= fac[q];

        // P -> LDS (C/D layout -> A layout via LDS; wave-private rows)
#pragma unroll
        for (int j = 0; j < 4; j++)
#pragma unroll
            for (int q = 0; q < 4; q++)
                ldsP[(wave * 16 + l4 * 4 + q) * 64 + j * 16 + l15] = f2bf(accs[j][q]);

        // PV : acc_o[16 q x 128 d]
#pragma unroll
        for (int s2 = 0; s2 < 2; s2++) {
            short8 pf = *(const short8*)&ldsP[(wave * 16 + l15) * 64 + s2 * 32 + (l4 << 3)];
#pragma unroll
            for (int n = 0; n < 8; n++) {
                short8 vf = *(const short8*)&ldsV[(n * 16 + l15) * 64 + s2 * 32 + (l4 << 3)];
                acco[n] = mfma_bf16(pf, vf, acco[n]);
            }
        }
        __syncthreads();
    }

    // epilogue: O[b*T+t][h*128+d] bf16
#pragma unroll
    for (int n = 0; n < 8; n++) {
        int row = b * T_ + qb * 64 + wave * 16 + l4 * 4;
        int col = h * 128 + n * 16 + l15;
#pragma unroll
        for (int q = 0; q < 4; q++)
            O[(size_t)(row + q) * C_ + col] = f2bf(acco[n][q] / lrow[q]);
    }
}

// ---------------------------------------------------------------- launch

extern "C" void kernel_launch(void* const* d_in, const int* in_sizes, int n_in,
                              void* d_out, int out_size, void* d_ws, size_t ws_size,
                              hipStream_t stream) {
    const float* x      = (const float*)d_in[0];
    const float* w_qkv  = (const float*)d_in[1];
    const float* w_out  = (const float*)d_in[2];
    const float* past_k = (const float*)d_in[3];
    const float* past_v = (const float*)d_in[4];
    float* out = (float*)d_out;

    char* ws = (char*)d_ws;
    u16* Xb    = (u16*)(ws);                            // 16 MB
    u16* Wqkvt = (u16*)(ws + 16777216);                 // 24 MB
    u16* Woutt = (u16*)(ws + 41943040);                 //  8 MB
    u16* QKVb  = (u16*)(ws + 50331648);                 // 48 MB
    u16* Kc    = (u16*)(ws + 100663296);                // 24 MB
    u16* Vt    = (u16*)(ws + 125829120);                // 24 MB
    u16* O     = (u16*)(ws + 150994944);                // 16 MB
    float* cosT = (float*)(ws + 167772160);             // 0.5 MB
    float* sinT = (float*)(ws + 168296448);             // 0.5 MB

    castx_kernel<<<(M_ * C_ / 4) / 256, 256, 0, stream>>>(x, Xb);
    wT_kernel<<<dim3(N3_ / 64, C_ / 64), 256, 0, stream>>>(w_qkv, Wqkvt, N3_, C_);
    wT_kernel<<<dim3(C_ / 64, C_ / 64), 256, 0, stream>>>(w_out, Woutt, C_, C_);
    rope_table_kernel<<<(T_ * 64) / 256, 256, 0, stream>>>(cosT, sinT);

    gemm_bt<u16><<<(M_ / 128) * (N3_ / 128), 256, 0, stream>>>(Xb, Wqkvt, QKVb, M_, N3_, C_);

    rope_qk_kernel<<<(B_ * T_ * H_ * 64) / 256, 256, 0, stream>>>(QKVb, Kc, cosT, sinT);
    pastk_kernel<<<(B_ * H_ * P_ * D_) / 256, 256, 0, stream>>>(past_k, Kc);
    vnewT_kernel<<<dim3(T_ / 64, 2, B_ * H_), 256, 0, stream>>>(QKVb, Vt);
    vpastT_kernel<<<dim3(P_ / 64, 2, B_ * H_), 256, 0, stream>>>(past_v, Vt);

    attn_kernel<<<B_ * H_ * (T_ / 64), 256, 0, stream>>>(QKVb, Kc, Vt, O);

    gemm_bt<float><<<(M_ / 128) * (C_ / 128), 256, 0, stream>>>(O, Woutt, out, M_, C_, C_);
}

// Round 2
// 563.578 us; speedup vs baseline: 1.1930x; 1.1930x over previous
//
#include <hip/hip_runtime.h>
#include <stdint.h>

#define B_ 2
#define T_ 2048
#define P_ 1024
#define H_ 16
#define D_ 128
#define C_ 2048
#define S_ 3072   // P_ + T_
#define M_ 4096   // B_*T_
#define N3_ 6144  // 3*C_

typedef unsigned short u16;
typedef __attribute__((ext_vector_type(8))) short short8;
typedef __attribute__((ext_vector_type(8))) __bf16 bf16x8;
typedef __attribute__((ext_vector_type(4))) float f32x4;
typedef __attribute__((ext_vector_type(4))) unsigned short u16x4;

static __device__ __forceinline__ float bf2f(u16 h) {
    union { unsigned int u; float f; } x; x.u = ((unsigned int)h) << 16; return x.f;
}
static __device__ __forceinline__ u16 f2bf(float f) {
    return __builtin_bit_cast(u16, (__bf16)f);   // v_cvt: RNE, 1 op
}

static __device__ __forceinline__ f32x4 mfma_bf16(short8 a, short8 b, f32x4 c) {
    return __builtin_amdgcn_mfma_f32_16x16x32_bf16(
        __builtin_bit_cast(bf16x8, a), __builtin_bit_cast(bf16x8, b), c, 0, 0, 0);
}

typedef __attribute__((address_space(3))) unsigned int lds_u32;
typedef const __attribute__((address_space(1))) unsigned int glb_u32;
static __device__ __forceinline__ void gload_lds16(const void* g, void* l) {
    __builtin_amdgcn_global_load_lds((glb_u32*)g, (lds_u32*)l, 16, 0, 0);
}

static __device__ __forceinline__ void storeC(float* p, float v) { *p = v; }
static __device__ __forceinline__ void storeC(u16* p, float v) { *p = f2bf(v); }

// ---------------------------------------------------------------- prep kernels

__global__ void castx_kernel(const float* __restrict__ x, u16* __restrict__ Xb) {
    int idx = blockIdx.x * 256 + threadIdx.x;          // over (M_*C_)/4
    const float4 v = ((const float4*)x)[idx];
    u16x4 o;
    o.x = f2bf(v.x); o.y = f2bf(v.y); o.z = f2bf(v.z); o.w = f2bf(v.w);
    ((u16x4*)Xb)[idx] = o;
}

// W[K,N] f32 -> Wt[N,K] bf16, 64x64 LDS tiles
__global__ void wT_kernel(const float* __restrict__ W, u16* __restrict__ Wt,
                          int Ndim, int Kdim) {
    __shared__ float tile[64][65];
    const int n0 = blockIdx.x * 64, k0 = blockIdx.y * 64;
    const int tid = threadIdx.x;
#pragma unroll
    for (int i = 0; i < 16; i++) {
        int idx = tid + i * 256;
        int r = idx >> 6, c = idx & 63;                // r: k, c: n
        tile[r][c] = W[(size_t)(k0 + r) * Ndim + n0 + c];
    }
    __syncthreads();
#pragma unroll
    for (int i = 0; i < 16; i++) {
        int idx = tid + i * 256;
        int r = idx >> 6, c = idx & 63;                // r: n, c: k
        Wt[(size_t)(n0 + r) * Kdim + k0 + c] = f2bf(tile[c][r]);
    }
}

__global__ void rope_table_kernel(float* __restrict__ cosT, float* __restrict__ sinT) {
    int idx = blockIdx.x * 256 + threadIdx.x;          // T_*64
    int t = idx >> 6, d = idx & 63;
    float inv = powf(10000.0f, -(float)d * (1.0f / 64.0f));
    float ang = (float)(P_ + t) * inv;
    cosT[idx] = cosf(ang);
    sinT[idx] = sinf(ang);
}

// RoPE Q in place; RoPE K and scatter into Kc[b,h,P_+t,d]
__global__ void rope_qk_kernel(u16* __restrict__ QKVb, u16* __restrict__ Kc,
                               const float* __restrict__ cosT,
                               const float* __restrict__ sinT) {
    int idx = blockIdx.x * 256 + threadIdx.x;          // B_*T_*H_*64
    int d = idx & 63;
    int h = (idx >> 6) & 15;
    int t = (idx >> 10) & 2047;
    int b = idx >> 21;
    size_t rowoff = (size_t)(b * T_ + t) * N3_;
    float c = cosT[(t << 6) + d], s = sinT[(t << 6) + d];
    {   // Q
        u16* p1 = QKVb + rowoff + h * 128 + d;
        float x1 = bf2f(p1[0]), x2 = bf2f(p1[64]);
        p1[0]  = f2bf(x1 * c - x2 * s);
        p1[64] = f2bf(x2 * c + x1 * s);
    }
    {   // K -> cache
        const u16* p1 = QKVb + rowoff + C_ + h * 128 + d;
        float x1 = bf2f(p1[0]), x2 = bf2f(p1[64]);
        u16* o = Kc + ((size_t)(b * H_ + h) * S_ + P_ + t) * 128 + d;
        o[0]  = f2bf(x1 * c - x2 * s);
        o[64] = f2bf(x2 * c + x1 * s);
    }
}

__global__ void pastk_kernel(const float* __restrict__ past_k, u16* __restrict__ Kc) {
    int idx = blockIdx.x * 256 + threadIdx.x;          // B_*H_*P_*D_
    int d = idx & 127;
    int p = (idx >> 7) & 1023;
    int bh = idx >> 17;
    Kc[((size_t)bh * S_ + p) * 128 + d] = f2bf(past_k[idx]);
}

// new V (bf16 in QKVb) -> Vt[b,h,d,P_+t]
__global__ void vnewT_kernel(const u16* __restrict__ QKVb, u16* __restrict__ Vt) {
    __shared__ u16 tile[64][65];
    const int t0 = blockIdx.x * 64, d0 = blockIdx.y * 64, bh = blockIdx.z;
    const int b = bh >> 4, h = bh & 15;
    const int tid = threadIdx.x;
#pragma unroll
    for (int i = 0; i < 16; i++) {
        int idx = tid + i * 256;
        int r = idx >> 6, c = idx & 63;                // r: t, c: d
        tile[r][c] = QKVb[(size_t)(b * T_ + t0 + r) * N3_ + 2 * C_ + h * 128 + d0 + c];
    }
    __syncthreads();
#pragma unroll
    for (int i = 0; i < 16; i++) {
        int idx = tid + i * 256;
        int r = idx >> 6, c = idx & 63;                // r: d, c: t
        Vt[((size_t)bh * 128 + d0 + r) * S_ + P_ + t0 + c] = tile[c][r];
    }
}

// past V f32 -> Vt[b,h,d,p]
__global__ void vpastT_kernel(const float* __restrict__ past_v, u16* __restrict__ Vt) {
    __shared__ float tile[64][65];
    const int p0 = blockIdx.x * 64, d0 = blockIdx.y * 64, bh = blockIdx.z;
    const int tid = threadIdx.x;
#pragma unroll
    for (int i = 0; i < 16; i++) {
        int idx = tid + i * 256;
        int r = idx >> 6, c = idx & 63;                // r: p, c: d
        tile[r][c] = past_v[((size_t)bh * P_ + p0 + r) * 128 + d0 + c];
    }
    __syncthreads();
#pragma unroll
    for (int i = 0; i < 16; i++) {
        int idx = tid + i * 256;
        int r = idx >> 6, c = idx & 63;                // r: d, c: p
        Vt[((size_t)bh * 128 + d0 + r) * S_ + p0 + c] = f2bf(tile[c][r]);
    }
}

// ---------------------------------------------------------------- GEMM
// C[M,N] = A[M,K] * Bt[N,K]^T ; bf16 in, OutT out. 128x128 tile, BK=64, 4 waves.
template <typename OutT>
__global__ void __launch_bounds__(256)
gemm_bt(const u16* __restrict__ A, const u16* __restrict__ Bt,
        OutT* __restrict__ Co, int Mdim, int Ndim, int Kdim) {
    __shared__ u16 ldsA[128 * 64];
    __shared__ u16 ldsB[128 * 64];
    const int nbx = Ndim >> 7;
    const int nwg = (Mdim >> 7) * nbx;
    int bid = blockIdx.x;
    int wg = (bid & 7) * (nwg >> 3) + (bid >> 3);      // XCD swizzle (nwg % 8 == 0)
    const int bm = wg / nbx, bn = wg % nbx;
    const int m0 = bm << 7, n0 = bn << 7;
    const int tid = threadIdx.x;
    const int wave = tid >> 6, lane = tid & 63;
    const int wr = wave >> 1, wc = wave & 1;

    f32x4 acc[4][4];
#pragma unroll
    for (int i = 0; i < 4; i++)
#pragma unroll
        for (int j = 0; j < 4; j++) acc[i][j] = (f32x4){0.f, 0.f, 0.f, 0.f};

    const int srow = wave * 32 + (lane >> 3);
    const int scol = (lane & 7) << 3;
    const u16* gA = A + (size_t)(m0 + srow) * Kdim + scol;
    const u16* gB = Bt + (size_t)(n0 + srow) * Kdim + scol;

    for (int k0 = 0; k0 < Kdim; k0 += 64) {
#pragma unroll
        for (int c = 0; c < 4; c++) {
            gload_lds16(gA + (size_t)(c * 8) * Kdim + k0, &ldsA[(wave * 32 + c * 8) * 64]);
            gload_lds16(gB + (size_t)(c * 8) * Kdim + k0, &ldsB[(wave * 32 + c * 8) * 64]);
        }
        __syncthreads();
#pragma unroll
        for (int kk = 0; kk < 2; kk++) {
            short8 af[4], bf[4];
#pragma unroll
            for (int i = 0; i < 4; i++) {
                int row = wr * 64 + i * 16 + (lane & 15);
                af[i] = *(const short8*)&ldsA[row * 64 + kk * 32 + ((lane >> 4) << 3)];
                int col = wc * 64 + i * 16 + (lane & 15);
                bf[i] = *(const short8*)&ldsB[col * 64 + kk * 32 + ((lane >> 4) << 3)];
            }
#pragma unroll
            for (int i = 0; i < 4; i++)
#pragma unroll
                for (int j = 0; j < 4; j++)
                    acc[i][j] = mfma_bf16(af[i], bf[j], acc[i][j]);
        }
        __syncthreads();
    }
#pragma unroll
    for (int i = 0; i < 4; i++)
#pragma unroll
        for (int j = 0; j < 4; j++) {
            int row = m0 + wr * 64 + i * 16 + ((lane >> 4) << 2);
            int col = n0 + wc * 64 + j * 16 + (lane & 15);
#pragma unroll
            for (int q = 0; q < 4; q++)
                storeC(&Co[(size_t)(row + q) * Ndim + col], acc[i][j][q]);
        }
}

// ---------------------------------------------------------------- attention
// Per block: one (b,h), 64 q rows. 4 waves x 16 q rows. KV block = 64.
// LDS tiles XOR-swizzled (T2): physical_byte = logical_byte ^ ((row&7)<<4).
// global_load_lds writes linearly -> pre-swizzle the per-lane GLOBAL source
// (rule #21: both-sides-or-neither).
__global__ void __launch_bounds__(256)
attn_kernel(const u16* __restrict__ QKVb, const u16* __restrict__ Kc,
            const u16* __restrict__ Vt, u16* __restrict__ O) {
    __shared__ u16 ldsK[64 * 128];   // rows 256B: swz bytes = ((row&7)<<4)
    __shared__ u16 ldsV[128 * 64];   // rows 128B: same swz
    __shared__ u16 ldsP[64 * 64];    // rows 128B: same swz

    const int nwg = B_ * H_ * (T_ / 64);               // 1024
    int bid = blockIdx.x;
    int wg = (bid & 7) * (nwg >> 3) + (bid >> 3);      // XCD swizzle
    const int qb = wg & 31;
    const int h = (wg >> 5) & 15;
    const int b = wg >> 9;
    const int tid = threadIdx.x, wave = tid >> 6, lane = tid & 63;
    const int l15 = lane & 15, l4 = lane >> 4;

    // ---- staging address precompute (per-lane, constant across tiles) ----
    const int p0 = wave * 64 + lane;                   // physical 16B-chunk id
    // K tile: 64 rows x 256B. chunk p -> row = p>>4; col perm const per lane.
    const int krow0 = p0 >> 4;                         // wave*4 + (lane>>4)
    const int kcolE = ((((lane & 15) << 4) ^ ((krow0 & 7) << 4)) >> 1);
    // V tile: 128 rows x 128B. chunk p -> row = p>>3.
    const int vrow0 = p0 >> 3;                         // wave*8 + (lane>>3)
    const int vcolE = ((((lane & 7) << 4) ^ ((vrow0 & 7) << 4)) >> 1);

    // Q fragments (A-operand), rows = wave*16 + l15
    short8 qf[4];
    {
        const u16* qptr = QKVb + (size_t)(b * T_ + qb * 64 + wave * 16 + l15) * N3_
                          + h * 128 + (l4 << 3);
#pragma unroll
        for (int s = 0; s < 4; s++) qf[s] = *(const short8*)(qptr + s * 32);
    }

    f32x4 acco[8];
#pragma unroll
    for (int n = 0; n < 8; n++) acco[n] = (f32x4){0.f, 0.f, 0.f, 0.f};
    float mrow[4], lrow[4];
#pragma unroll
    for (int q = 0; q < 4; q++) { mrow[q] = -1e30f; lrow[q] = 0.f; }

    const u16* Kbh = Kc + (size_t)(b * H_ + h) * S_ * 128;
    const u16* Vbh = Vt + (size_t)(b * H_ + h) * 128 * S_;
    const float sl2 = 0.08838834764831845f * 1.4426950408889634f; // scale*log2e

    // prologue: stage K[0], V[0]
#pragma unroll
    for (int c = 0; c < 4; c++) {
        gload_lds16(Kbh + (size_t)(krow0 + c * 16) * 128 + kcolE,
                    (char*)ldsK + c * 4096 + wave * 1024);
        gload_lds16(Vbh + (size_t)(vrow0 + c * 32) * S_ + vcolE,
                    (char*)ldsV + c * 4096 + wave * 1024);
    }
    __syncthreads();

    const int kswzb = (l15 & 7) << 4;                  // read-side swz (R&7)<<4

    for (int s0 = 0; s0 < S_; s0 += 64) {
        // ---- QK^T : 16 q rows x 64 keys (reads ldsK) ----
        f32x4 accs[4];
#pragma unroll
        for (int j = 0; j < 4; j++) accs[j] = (f32x4){0.f, 0.f, 0.f, 0.f};
#pragma unroll
        for (int s = 0; s < 4; s++)
#pragma unroll
            for (int j = 0; j < 4; j++) {
                int R = j * 16 + l15;
                int colb = s * 64 + (l4 << 4);
                int idx = ((R << 8) + (colb ^ kswzb)) >> 1;
                short8 kf = *(const short8*)&ldsK[idx];
                accs[j] = mfma_bf16(qf[s], kf, accs[j]);
            }

        __syncthreads();   // A: all waves done with ldsK; drains V[t] loads

        // issue K[t+1] (in flight across softmax+PV, drained at barrier B)
        if (s0 + 64 < S_) {
#pragma unroll
            for (int c = 0; c < 4; c++)
                gload_lds16(Kbh + (size_t)(s0 + 64 + krow0 + c * 16) * 128 + kcolE,
                            (char*)ldsK + c * 4096 + wave * 1024);
        }

        // ---- online softmax (exp2 domain) ----
        float pmax[4];
#pragma unroll
        for (int q = 0; q < 4; q++) {
            float v = fmaxf(fmaxf(accs[0][q], accs[1][q]), fmaxf(accs[2][q], accs[3][q]));
#pragma unroll
            for (int off = 8; off >= 1; off >>= 1) v = fmaxf(v, __shfl_xor(v, off));
            pmax[q] = v * sl2;
        }
        float fac[4];
#pragma unroll
        for (int q = 0; q < 4; q++) {
            float mn = fmaxf(mrow[q], pmax[q]);
            fac[q] = exp2f(mrow[q] - mn);
            mrow[q] = mn;
        }
#pragma unroll
        for (int j = 0; j < 4; j++)
#pragma unroll
            for (int q = 0; q < 4; q++)
                accs[j][q] = exp2f(accs[j][q] * sl2 - mrow[q]);
#pragma unroll
        for (int q = 0; q < 4; q++) {
            float s = accs[0][q] + accs[1][q] + accs[2][q] + accs[3][q];
#pragma unroll
            for (int off = 8; off >= 1; off >>= 1) s += __shfl_xor(s, off);
            lrow[q] = lrow[q] * fac[q] + s;
        }
#pragma unroll
        for (int n = 0; n < 8; n++)
#pragma unroll
            for (int q = 0; q < 4; q++) acco[n][q] *= fac[q];

        // ---- P -> LDS (swizzled; wave-private rows, no barrier needed) ----
#pragma unroll
        for (int j = 0; j < 4; j++)
#pragma unroll
            for (int q = 0; q < 4; q++) {
                int row = wave * 16 + l4 * 4 + q;
                int colb = (j * 16 + l15) << 1;
                int idx = (((row << 7) + colb) ^ ((row & 7) << 4)) >> 1;
                ldsP[idx] = f2bf(accs[j][q]);
            }

        // ---- PV : acc_o[16 q x 128 d] (reads ldsP, ldsV) ----
#pragma unroll
        for (int s2 = 0; s2 < 2; s2++) {
            int colb = s2 * 64 + (l4 << 4);
            int pidx = (((wave * 16 + l15) << 7) + (colb ^ kswzb)) >> 1;
            short8 pf = *(const short8*)&ldsP[pidx];
#pragma unroll
            for (int n = 0; n < 8; n++) {
                int vidx = (((n * 16 + l15) << 7) + (colb ^ kswzb)) >> 1;
                short8 vf = *(const short8*)&ldsV[vidx];
                acco[n] = mfma_bf16(pf, vf, acco[n]);
            }
        }

        __syncthreads();   // B: all waves done with ldsV/ldsP; drains K[t+1]

        // issue V[t+1] (in flight across next QK^T, drained at next barrier A)
        if (s0 + 64 < S_) {
#pragma unroll
            for (int c = 0; c < 4; c++)
                gload_lds16(Vbh + (size_t)(vrow0 + c * 32) * S_ + s0 + 64 + vcolE,
                            (char*)ldsV + c * 4096 + wave * 1024);
        }
    }

    // epilogue: O[b*T+t][h*128+d] bf16
    float rl[4];
#pragma unroll
    for (int q = 0; q < 4; q++) rl[q] = 1.0f / lrow[q];
#pragma unroll
    for (int n = 0; n < 8; n++) {
        int row = b * T_ + qb * 64 + wave * 16 + l4 * 4;
        int col = h * 128 + n * 16 + l15;
#pragma unroll
        for (int q = 0; q < 4; q++)
            O[(size_t)(row + q) * C_ + col] = f2bf(acco[n][q] * rl[q]);
    }
}

// ---------------------------------------------------------------- launch

extern "C" void kernel_launch(void* const* d_in, const int* in_sizes, int n_in,
                              void* d_out, int out_size, void* d_ws, size_t ws_size,
                              hipStream_t stream) {
    const float* x      = (const float*)d_in[0];
    const float* w_qkv  = (const float*)d_in[1];
    const float* w_out  = (const float*)d_in[2];
    const float* past_k = (const float*)d_in[3];
    const float* past_v = (const float*)d_in[4];
    float* out = (float*)d_out;

    char* ws = (char*)d_ws;
    u16* Xb    = (u16*)(ws);                            // 16 MB
    u16* Wqkvt = (u16*)(ws + 16777216);                 // 24 MB
    u16* Woutt = (u16*)(ws + 41943040);                 //  8 MB
    u16* QKVb  = (u16*)(ws + 50331648);                 // 48 MB
    u16* Kc    = (u16*)(ws + 100663296);                // 24 MB
    u16* Vt    = (u16*)(ws + 125829120);                // 24 MB
    u16* O     = (u16*)(ws + 150994944);                // 16 MB
    float* cosT = (float*)(ws + 167772160);             // 0.5 MB
    float* sinT = (float*)(ws + 168296448);             // 0.5 MB

    castx_kernel<<<(M_ * C_ / 4) / 256, 256, 0, stream>>>(x, Xb);
    wT_kernel<<<dim3(N3_ / 64, C_ / 64), 256, 0, stream>>>(w_qkv, Wqkvt, N3_, C_);
    wT_kernel<<<dim3(C_ / 64, C_ / 64), 256, 0, stream>>>(w_out, Woutt, C_, C_);
    rope_table_kernel<<<(T_ * 64) / 256, 256, 0, stream>>>(cosT, sinT);

    gemm_bt<u16><<<(M_ / 128) * (N3_ / 128), 256, 0, stream>>>(Xb, Wqkvt, QKVb, M_, N3_, C_);

    rope_qk_kernel<<<(B_ * T_ * H_ * 64) / 256, 256, 0, stream>>>(QKVb, Kc, cosT, sinT);
    pastk_kernel<<<(B_ * H_ * P_ * D_) / 256, 256, 0, stream>>>(past_k, Kc);
    vnewT_kernel<<<dim3(T_ / 64, 2, B_ * H_), 256, 0, stream>>>(QKVb, Vt);
    vpastT_kernel<<<dim3(P_ / 64, 2, B_ * H_), 256, 0, stream>>>(past_v, Vt);

    attn_kernel<<<B_ * H_ * (T_ / 64), 256, 0, stream>>>(QKVb, Kc, Vt, O);

    gemm_bt<float><<<(M_ / 128) * (C_ / 128), 256, 0, stream>>>(O, Woutt, out, M_, C_, C_);
}

// Round 3
// 423.870 us; speedup vs baseline: 1.5861x; 1.3296x over previous
//
#include <hip/hip_runtime.h>
#include <stdint.h>

#define B_ 2
#define T_ 2048
#define P_ 1024
#define H_ 16
#define D_ 128
#define C_ 2048
#define S_ 3072   // P_ + T_
#define M_ 4096   // B_*T_
#define N3_ 6144  // 3*C_

typedef unsigned short u16;
typedef unsigned int uint32;
typedef __attribute__((ext_vector_type(8))) short short8;
typedef __attribute__((ext_vector_type(8))) __bf16 bf16x8;
typedef __attribute__((ext_vector_type(4))) float f32x4;
typedef __attribute__((ext_vector_type(16))) float f32x16;
typedef __attribute__((ext_vector_type(4))) unsigned short u16x4;
typedef __attribute__((ext_vector_type(4))) unsigned int uint4v;

static __device__ __forceinline__ float bf2f(u16 h) {
    union { unsigned int u; float f; } x; x.u = ((unsigned int)h) << 16; return x.f;
}
static __device__ __forceinline__ u16 f2bf(float f) {
    return __builtin_bit_cast(u16, (__bf16)f);   // v_cvt: RNE, 1 op
}
static __device__ __forceinline__ uint32 pkbf(float x, float y) {
    return (uint32)f2bf(x) | ((uint32)f2bf(y) << 16);
}

static __device__ __forceinline__ f32x4 mfma_bf16(short8 a, short8 b, f32x4 c) {
    return __builtin_amdgcn_mfma_f32_16x16x32_bf16(
        __builtin_bit_cast(bf16x8, a), __builtin_bit_cast(bf16x8, b), c, 0, 0, 0);
}
static __device__ __forceinline__ f32x16 mfma32(short8 a, short8 b, f32x16 c) {
    return __builtin_amdgcn_mfma_f32_32x32x16_bf16(
        __builtin_bit_cast(bf16x8, a), __builtin_bit_cast(bf16x8, b), c, 0, 0, 0);
}

typedef __attribute__((address_space(3))) unsigned int lds_u32;
typedef const __attribute__((address_space(1))) unsigned int glb_u32;
static __device__ __forceinline__ void gload_lds16(const void* g, void* l) {
    __builtin_amdgcn_global_load_lds((glb_u32*)g, (lds_u32*)l, 16, 0, 0);
}

static __device__ __forceinline__ void storeC(float* p, float v) { *p = v; }
static __device__ __forceinline__ void storeC(u16* p, float v) { *p = f2bf(v); }

// ---------------------------------------------------------------- prep kernels

__global__ void castx_kernel(const float* __restrict__ x, u16* __restrict__ Xb) {
    int idx = blockIdx.x * 256 + threadIdx.x;          // over (M_*C_)/4
    const float4 v = ((const float4*)x)[idx];
    u16x4 o;
    o.x = f2bf(v.x); o.y = f2bf(v.y); o.z = f2bf(v.z); o.w = f2bf(v.w);
    ((u16x4*)Xb)[idx] = o;
}

// W[K,N] f32 -> Wt[N,K] bf16, 64x64 LDS tiles
__global__ void wT_kernel(const float* __restrict__ W, u16* __restrict__ Wt,
                          int Ndim, int Kdim) {
    __shared__ float tile[64][65];
    const int n0 = blockIdx.x * 64, k0 = blockIdx.y * 64;
    const int tid = threadIdx.x;
#pragma unroll
    for (int i = 0; i < 16; i++) {
        int idx = tid + i * 256;
        int r = idx >> 6, c = idx & 63;                // r: k, c: n
        tile[r][c] = W[(size_t)(k0 + r) * Ndim + n0 + c];
    }
    __syncthreads();
#pragma unroll
    for (int i = 0; i < 16; i++) {
        int idx = tid + i * 256;
        int r = idx >> 6, c = idx & 63;                // r: n, c: k
        Wt[(size_t)(n0 + r) * Kdim + k0 + c] = f2bf(tile[c][r]);
    }
}

__global__ void rope_table_kernel(float* __restrict__ cosT, float* __restrict__ sinT) {
    int idx = blockIdx.x * 256 + threadIdx.x;          // T_*64
    int t = idx >> 6, d = idx & 63;
    float inv = powf(10000.0f, -(float)d * (1.0f / 64.0f));
    float ang = (float)(P_ + t) * inv;
    cosT[idx] = cosf(ang);
    sinT[idx] = sinf(ang);
}

// RoPE Q in place; RoPE K and scatter into Kc[b,h,P_+t,d]
__global__ void rope_qk_kernel(u16* __restrict__ QKVb, u16* __restrict__ Kc,
                               const float* __restrict__ cosT,
                               const float* __restrict__ sinT) {
    int idx = blockIdx.x * 256 + threadIdx.x;          // B_*T_*H_*64
    int d = idx & 63;
    int h = (idx >> 6) & 15;
    int t = (idx >> 10) & 2047;
    int b = idx >> 21;
    size_t rowoff = (size_t)(b * T_ + t) * N3_;
    float c = cosT[(t << 6) + d], s = sinT[(t << 6) + d];
    {   // Q
        u16* p1 = QKVb + rowoff + h * 128 + d;
        float x1 = bf2f(p1[0]), x2 = bf2f(p1[64]);
        p1[0]  = f2bf(x1 * c - x2 * s);
        p1[64] = f2bf(x2 * c + x1 * s);
    }
    {   // K -> cache
        const u16* p1 = QKVb + rowoff + C_ + h * 128 + d;
        float x1 = bf2f(p1[0]), x2 = bf2f(p1[64]);
        u16* o = Kc + ((size_t)(b * H_ + h) * S_ + P_ + t) * 128 + d;
        o[0]  = f2bf(x1 * c - x2 * s);
        o[64] = f2bf(x2 * c + x1 * s);
    }
}

__global__ void pastk_kernel(const float* __restrict__ past_k, u16* __restrict__ Kc) {
    int idx = blockIdx.x * 256 + threadIdx.x;          // B_*H_*P_*D_
    int d = idx & 127;
    int p = (idx >> 7) & 1023;
    int bh = idx >> 17;
    Kc[((size_t)bh * S_ + p) * 128 + d] = f2bf(past_k[idx]);
}

// new V (bf16 in QKVb) -> Vt[b,h,d,P_+t]
__global__ void vnewT_kernel(const u16* __restrict__ QKVb, u16* __restrict__ Vt) {
    __shared__ u16 tile[64][65];
    const int t0 = blockIdx.x * 64, d0 = blockIdx.y * 64, bh = blockIdx.z;
    const int b = bh >> 4, h = bh & 15;
    const int tid = threadIdx.x;
#pragma unroll
    for (int i = 0; i < 16; i++) {
        int idx = tid + i * 256;
        int r = idx >> 6, c = idx & 63;                // r: t, c: d
        tile[r][c] = QKVb[(size_t)(b * T_ + t0 + r) * N3_ + 2 * C_ + h * 128 + d0 + c];
    }
    __syncthreads();
#pragma unroll
    for (int i = 0; i < 16; i++) {
        int idx = tid + i * 256;
        int r = idx >> 6, c = idx & 63;                // r: d, c: t
        Vt[((size_t)bh * 128 + d0 + r) * S_ + P_ + t0 + c] = tile[c][r];
    }
}

// past V f32 -> Vt[b,h,d,p]
__global__ void vpastT_kernel(const float* __restrict__ past_v, u16* __restrict__ Vt) {
    __shared__ float tile[64][65];
    const int p0 = blockIdx.x * 64, d0 = blockIdx.y * 64, bh = blockIdx.z;
    const int tid = threadIdx.x;
#pragma unroll
    for (int i = 0; i < 16; i++) {
        int idx = tid + i * 256;
        int r = idx >> 6, c = idx & 63;                // r: p, c: d
        tile[r][c] = past_v[((size_t)bh * P_ + p0 + r) * 128 + d0 + c];
    }
    __syncthreads();
#pragma unroll
    for (int i = 0; i < 16; i++) {
        int idx = tid + i * 256;
        int r = idx >> 6, c = idx & 63;                // r: d, c: p
        Vt[((size_t)bh * 128 + d0 + r) * S_ + p0 + c] = f2bf(tile[c][r]);
    }
}

// ---------------------------------------------------------------- GEMM
// C[M,N] = A[M,K] * Bt[N,K]^T ; bf16 in, OutT out. 128x128 tile, BK=64, 4 waves.
template <typename OutT>
__global__ void __launch_bounds__(256)
gemm_bt(const u16* __restrict__ A, const u16* __restrict__ Bt,
        OutT* __restrict__ Co, int Mdim, int Ndim, int Kdim) {
    __shared__ u16 ldsA[128 * 64];
    __shared__ u16 ldsB[128 * 64];
    const int nbx = Ndim >> 7;
    const int nwg = (Mdim >> 7) * nbx;
    int bid = blockIdx.x;
    int wg = (bid & 7) * (nwg >> 3) + (bid >> 3);      // XCD swizzle (nwg % 8 == 0)
    const int bm = wg / nbx, bn = wg % nbx;
    const int m0 = bm << 7, n0 = bn << 7;
    const int tid = threadIdx.x;
    const int wave = tid >> 6, lane = tid & 63;
    const int wr = wave >> 1, wc = wave & 1;

    f32x4 acc[4][4];
#pragma unroll
    for (int i = 0; i < 4; i++)
#pragma unroll
        for (int j = 0; j < 4; j++) acc[i][j] = (f32x4){0.f, 0.f, 0.f, 0.f};

    const int srow = wave * 32 + (lane >> 3);
    const int scol = (lane & 7) << 3;
    const u16* gA = A + (size_t)(m0 + srow) * Kdim + scol;
    const u16* gB = Bt + (size_t)(n0 + srow) * Kdim + scol;

    for (int k0 = 0; k0 < Kdim; k0 += 64) {
#pragma unroll
        for (int c = 0; c < 4; c++) {
            gload_lds16(gA + (size_t)(c * 8) * Kdim + k0, &ldsA[(wave * 32 + c * 8) * 64]);
            gload_lds16(gB + (size_t)(c * 8) * Kdim + k0, &ldsB[(wave * 32 + c * 8) * 64]);
        }
        __syncthreads();
#pragma unroll
        for (int kk = 0; kk < 2; kk++) {
            short8 af[4], bf[4];
#pragma unroll
            for (int i = 0; i < 4; i++) {
                int row = wr * 64 + i * 16 + (lane & 15);
                af[i] = *(const short8*)&ldsA[row * 64 + kk * 32 + ((lane >> 4) << 3)];
                int col = wc * 64 + i * 16 + (lane & 15);
                bf[i] = *(const short8*)&ldsB[col * 64 + kk * 32 + ((lane >> 4) << 3)];
            }
#pragma unroll
            for (int i = 0; i < 4; i++)
#pragma unroll
                for (int j = 0; j < 4; j++)
                    acc[i][j] = mfma_bf16(af[i], bf[j], acc[i][j]);
        }
        __syncthreads();
    }
#pragma unroll
    for (int i = 0; i < 4; i++)
#pragma unroll
        for (int j = 0; j < 4; j++) {
            int row = m0 + wr * 64 + i * 16 + ((lane >> 4) << 2);
            int col = n0 + wc * 64 + j * 16 + (lane & 15);
#pragma unroll
            for (int q = 0; q < 4; q++)
                storeC(&Co[(size_t)(row + q) * Ndim + col], acc[i][j][q]);
        }
}

// ---------------------------------------------------------------- attention
// m214-style: 8 waves x 32 q-rows = 256 q/block; one (b,h) slice per block.
// Swapped QK^T (mfma(K,Q)): P C-frag has q = lane&31, k reg-mapped -> softmax
// fully in-register (1 shfl_xor(32) per reduce). Swapped PV (mfma(V^T,P^T)):
// O^T C-frag has q = lane&31 -> rescale factor lane-local. No P LDS buffer.
// K/V double-buffered LDS, XOR-swizzle ((row&7)<<4) both-sides (rule #21).
__global__ void __launch_bounds__(512, 2)
attn_kernel(const u16* __restrict__ QKVb, const u16* __restrict__ Kc,
            const u16* __restrict__ Vt, u16* __restrict__ O) {
    __shared__ u16 ldsK[2][64 * 128];   // [buf][64 k][128 d], rows 256B
    __shared__ u16 ldsV[2][128 * 64];   // [buf][128 d][64 k], rows 128B

    int bid = blockIdx.x;                              // 256 blocks
    int wg = (bid & 7) * 32 + (bid >> 3);              // XCD swizzle (bijective)
    const int qc = wg & 7;                             // q-chunk (8 x 256 rows)
    const int bh = wg >> 3;
    const int b = bh >> 4, h = bh & 15;
    const int tid = threadIdx.x, wave = tid >> 6, lane = tid & 63;
    const int l31 = lane & 31, hi = lane >> 5;

    // staging constants (source pre-swizzled; LDS dest linear)
    const int krow = tid >> 4;                                         // 0..31
    const int kcol = (((tid & 15) << 4) ^ ((krow & 7) << 4)) >> 1;
    const int vrow = tid >> 3;                                         // 0..63
    const int vcol = (((tid & 7) << 4) ^ ((vrow & 7) << 4)) >> 1;

    const u16* Kbh = Kc + (size_t)bh * S_ * 128;
    const u16* Vbh = Vt + (size_t)bh * 128 * S_;

    const int tq = qc * 256 + wave * 32 + l31;         // this lane's q row
    // Q fragments: Q[q=l31][d = ks*16 + hi*8 + e], 8 x bf16x8
    short8 qf[8];
    {
        const u16* qp = QKVb + (size_t)(b * T_ + tq) * N3_ + h * 128 + hi * 8;
#pragma unroll
        for (int ks = 0; ks < 8; ks++) qf[ks] = *(const short8*)(qp + ks * 16);
    }

    f32x16 acco[4];                                    // O^T: col q=l31, row d
#pragma unroll
    for (int d = 0; d < 4; d++) acco[d] = (f32x16)(0.0f);
    float mrow = -1e30f, lrow = 0.f;                   // per-lane (q = l31)
    const float sl2 = 0.08838834764831845f * 1.4426950408889634f;

#define STAGE(bufi, tt) do {                                                    \
    const int _s0 = (tt) * 64;                                                  \
    gload_lds16(Kbh + (size_t)(_s0 + krow) * 128 + kcol,                        \
                (char*)&ldsK[bufi][0] + wave * 1024);                           \
    gload_lds16(Kbh + (size_t)(_s0 + krow + 32) * 128 + kcol,                   \
                (char*)&ldsK[bufi][0] + 8192 + wave * 1024);                    \
    gload_lds16(Vbh + (size_t)vrow * S_ + _s0 + vcol,                           \
                (char*)&ldsV[bufi][0] + wave * 1024);                           \
    gload_lds16(Vbh + (size_t)(vrow + 64) * S_ + _s0 + vcol,                    \
                (char*)&ldsV[bufi][0] + 8192 + wave * 1024);                    \
} while (0)

    STAGE(0, 0);
    __syncthreads();

    const int swz = (l31 & 7) << 4;                    // read-side swizzle

    for (int t = 0; t < S_ / 64; ++t) {
        const int cur = t & 1;
        if (t < S_ / 64 - 1) STAGE(cur ^ 1, t + 1);

        const u16* Kl = ldsK[cur];
        const u16* Vl = ldsV[cur];

        // ---- QK^T: p0 (k 0..31), p1 (k 32..63); contraction d ----
        f32x16 p0 = (f32x16)(0.0f), p1 = (f32x16)(0.0f);
        __builtin_amdgcn_s_setprio(1);
#pragma unroll
        for (int ks = 0; ks < 8; ks++) {
            const int cidx = (((ks * 32 + hi * 16) ^ swz) >> 1);
            short8 k0 = *(const short8*)&Kl[(l31 << 7) + cidx];
            short8 k1 = *(const short8*)&Kl[((32 + l31) << 7) + cidx];
            p0 = mfma32(k0, qf[ks], p0);
            p1 = mfma32(k1, qf[ks], p1);
        }
        __builtin_amdgcn_s_setprio(0);

        // ---- online softmax, in-register (q = l31) ----
        float pm = fmaxf(p0[0], p0[1]);
#pragma unroll
        for (int r = 2; r < 16; r++) pm = fmaxf(pm, p0[r]);
#pragma unroll
        for (int r = 0; r < 16; r++) pm = fmaxf(pm, p1[r]);
        pm = fmaxf(pm, __shfl_xor(pm, 32));
        float pmS = pm * sl2;
        if (!__all(pmS <= mrow + 8.0f)) {              // T13 defer-max
            float mn = fmaxf(mrow, pmS);
            float fac = exp2f(mrow - mn);
            mrow = mn;
            lrow *= fac;
#pragma unroll
            for (int d = 0; d < 4; d++)
#pragma unroll
                for (int r = 0; r < 16; r++) acco[d][r] *= fac;
        }
        float sum = 0.f;
#pragma unroll
        for (int r = 0; r < 16; r++) { p0[r] = exp2f(fmaf(p0[r], sl2, -mrow)); sum += p0[r]; }
#pragma unroll
        for (int r = 0; r < 16; r++) { p1[r] = exp2f(fmaf(p1[r], sl2, -mrow)); sum += p1[r]; }
        sum += __shfl_xor(sum, 32);
        lrow += sum;

        // ---- P (C-layout) -> PV B-frags, in-register (T12 via shfl) ----
        // k_local(reg,hi) = (reg&3) + 8*(reg>>2) + 4*hi; frag e -> k = ks*16+hi*8+e
        uint32 w[4][4];
#define PACK_HALF(pp, kh, ksout) do {                                           \
    uint32 A0 = pkbf(pp[(kh)*8 + 0], pp[(kh)*8 + 1]);                           \
    uint32 A1 = pkbf(pp[(kh)*8 + 2], pp[(kh)*8 + 3]);                           \
    uint32 B0 = pkbf(pp[(kh)*8 + 4], pp[(kh)*8 + 5]);                           \
    uint32 B1 = pkbf(pp[(kh)*8 + 6], pp[(kh)*8 + 7]);                           \
    uint32 sA0 = __shfl_xor(A0, 32), sA1 = __shfl_xor(A1, 32);                  \
    uint32 sB0 = __shfl_xor(B0, 32), sB1 = __shfl_xor(B1, 32);                  \
    w[ksout][0] = hi ? sB0 : A0;                                                \
    w[ksout][1] = hi ? sB1 : A1;                                                \
    w[ksout][2] = hi ? B0 : sA0;                                                \
    w[ksout][3] = hi ? B1 : sA1;                                                \
} while (0)
        PACK_HALF(p0, 0, 0);
        PACK_HALF(p0, 1, 1);
        PACK_HALF(p1, 0, 2);
        PACK_HALF(p1, 1, 3);
#undef PACK_HALF

        // ---- PV: O^T[d][q] += V^T[d][k] * P^T[k][q] ----
        __builtin_amdgcn_s_setprio(1);
#pragma unroll
        for (int ks = 0; ks < 4; ks++) {
            uint4v pw = {w[ks][0], w[ks][1], w[ks][2], w[ks][3]};
            short8 pf = __builtin_bit_cast(short8, pw);
            const int cidx = (((ks * 32 + hi * 16) ^ swz) >> 1);
#pragma unroll
            for (int dblk = 0; dblk < 4; dblk++) {
                short8 vf = *(const short8*)&Vl[((dblk * 32 + l31) << 6) + cidx];
                acco[dblk] = mfma32(vf, pf, acco[dblk]);
            }
        }
        __builtin_amdgcn_s_setprio(0);

        __syncthreads();   // readers done with cur; stage(cur^1) drained
    }
#undef STAGE

    // ---- epilogue: O[b*T+tq][h*128+d], d = dblk*32 + 8*j + 4*hi + {0..3} ----
    float rl = 1.0f / lrow;
    u16* Op = O + (size_t)(b * T_ + tq) * C_ + h * 128;
#pragma unroll
    for (int dblk = 0; dblk < 4; dblk++)
#pragma unroll
        for (int j = 0; j < 4; j++) {
            u16x4 o;
            o.x = f2bf(acco[dblk][4 * j + 0] * rl);
            o.y = f2bf(acco[dblk][4 * j + 1] * rl);
            o.z = f2bf(acco[dblk][4 * j + 2] * rl);
            o.w = f2bf(acco[dblk][4 * j + 3] * rl);
            *(u16x4*)(Op + dblk * 32 + j * 8 + hi * 4) = o;
        }
}

// ---------------------------------------------------------------- launch

extern "C" void kernel_launch(void* const* d_in, const int* in_sizes, int n_in,
                              void* d_out, int out_size, void* d_ws, size_t ws_size,
                              hipStream_t stream) {
    const float* x      = (const float*)d_in[0];
    const float* w_qkv  = (const float*)d_in[1];
    const float* w_out  = (const float*)d_in[2];
    const float* past_k = (const float*)d_in[3];
    const float* past_v = (const float*)d_in[4];
    float* out = (float*)d_out;

    char* ws = (char*)d_ws;
    u16* Xb    = (u16*)(ws);                            // 16 MB
    u16* Wqkvt = (u16*)(ws + 16777216);                 // 24 MB
    u16* Woutt = (u16*)(ws + 41943040);                 //  8 MB
    u16* QKVb  = (u16*)(ws + 50331648);                 // 48 MB
    u16* Kc    = (u16*)(ws + 100663296);                // 24 MB
    u16* Vt    = (u16*)(ws + 125829120);                // 24 MB
    u16* O     = (u16*)(ws + 150994944);                // 16 MB
    float* cosT = (float*)(ws + 167772160);             // 0.5 MB
    float* sinT = (float*)(ws + 168296448);             // 0.5 MB

    castx_kernel<<<(M_ * C_ / 4) / 256, 256, 0, stream>>>(x, Xb);
    wT_kernel<<<dim3(N3_ / 64, C_ / 64), 256, 0, stream>>>(w_qkv, Wqkvt, N3_, C_);
    wT_kernel<<<dim3(C_ / 64, C_ / 64), 256, 0, stream>>>(w_out, Woutt, C_, C_);
    rope_table_kernel<<<(T_ * 64) / 256, 256, 0, stream>>>(cosT, sinT);

    gemm_bt<u16><<<(M_ / 128) * (N3_ / 128), 256, 0, stream>>>(Xb, Wqkvt, QKVb, M_, N3_, C_);

    rope_qk_kernel<<<(B_ * T_ * H_ * 64) / 256, 256, 0, stream>>>(QKVb, Kc, cosT, sinT);
    pastk_kernel<<<(B_ * H_ * P_ * D_) / 256, 256, 0, stream>>>(past_k, Kc);
    vnewT_kernel<<<dim3(T_ / 64, 2, B_ * H_), 256, 0, stream>>>(QKVb, Vt);
    vpastT_kernel<<<dim3(P_ / 64, 2, B_ * H_), 256, 0, stream>>>(past_v, Vt);

    attn_kernel<<<256, 512, 0, stream>>>(QKVb, Kc, Vt, O);

    gemm_bt<float><<<(M_ / 128) * (C_ / 128), 256, 0, stream>>>(O, Woutt, out, M_, C_, C_);
}